// Round 19
// baseline (158.392 us; speedup 1.0000x reference)
//
#include <hip/hip_runtime.h>
#include <hip/hip_bf16.h>

#define B_   8
#define C1_  256
#define C2_  256
#define Cm_  128    // C_ = C2/2
#define H_   80
#define W_   80
#define HW_  6400
#define CN_  1152   // C_ * 9
#define EPS_ 1e-5f
#define LOG2E_ 1.4426950408889634f

typedef __attribute__((ext_vector_type(8))) short bf16x8;
typedef __attribute__((ext_vector_type(4))) float f32x4;

__device__ inline unsigned short f2bf(float f) {
  union { float f; unsigned int u; } v; v.f = f;
  unsigned int u = v.u;
  unsigned int r = (u + 0x7FFFu + ((u >> 16) & 1u)) >> 16;
  return (unsigned short)r;
}
__device__ inline float bf2f(unsigned short s) {
  union { unsigned int u; float f; } v; v.u = ((unsigned int)s) << 16;
  return v.f;
}

__device__ __forceinline__ void gload16(const void* g, void* l) {
  __builtin_amdgcn_global_load_lds(
      (const __attribute__((address_space(1))) void*)g,
      (__attribute__((address_space(3))) void*)l, 16, 0, 0);
}

// ---- Kernel 0: prep (round-17; Wgt/bgt folded with LOG2E) ------------------
__global__ __launch_bounds__(256) void k0_prep(
    const float* __restrict__ Wc, const float* __restrict__ bc,
    const float* __restrict__ g2, const float* __restrict__ b2,
    const float* __restrict__ m2, const float* __restrict__ v2,
    const float* __restrict__ Wg, const float* __restrict__ bg,
    const float* __restrict__ gg, const float* __restrict__ bgw,
    const float* __restrict__ mg, const float* __restrict__ vg,
    const float* __restrict__ W1,
    unsigned short* __restrict__ Wcb, float* __restrict__ A2,
    float* __restrict__ B2, float* __restrict__ Wgt,
    float* __restrict__ bgt, unsigned short* __restrict__ W1b) {
  int idx = blockIdx.x * 256 + threadIdx.x;
  if (idx < C2_ * CN_) {
    int o = idx / CN_;
    int r = idx - o * CN_;
    int n = r >> 7;          // 0..8
    int c = r & 127;         // 0..127
    Wcb[idx] = f2bf(Wc[o * CN_ + c * 9 + n]);
  }
  if (idx < Cm_ * 81) {
    int c  = idx / 81;
    int oi = idx - c * 81;
    int n  = oi / 9;
    float sg = gg[c * 9 + n] * rsqrtf(vg[c * 9 + n] + EPS_);
    Wgt[oi * 128 + c] = Wg[idx] * sg * LOG2E_;
  }
  if (idx < Cm_ * 9) {
    int c = idx / 9;
    int n = idx - c * 9;
    float sg = gg[idx] * rsqrtf(vg[idx] + EPS_);
    bgt[n * 128 + c] = ((bg[idx] - mg[idx]) * sg + bgw[idx]) * LOG2E_;
  }
  if (idx < Cm_ * C1_) W1b[idx] = f2bf(W1[idx]);
  if (idx < C2_) {
    float s = g2[idx] * rsqrtf(v2[idx] + EPS_);
    A2[idx] = s;
    B2[idx] = (bc[idx] - m2[idx]) * s + b2[idx];
  }
}

// ---------------- Kernel 1: h = SiLU(BN1(W1b @ x)) via MFMA (round-12) ------
__global__ __launch_bounds__(256) void k1_cv1(
    const float* __restrict__ x, const unsigned short* __restrict__ W1b,
    const float* __restrict__ g1, const float* __restrict__ b1,
    const float* __restrict__ m1, const float* __restrict__ v1,
    unsigned short* __restrict__ h) {
  __shared__ alignas(16) unsigned short Ash[2][128 * 64];
  __shared__ alignas(16) unsigned short Bsh[2][64 * 64];

  const int b   = blockIdx.y;
  const int hw0 = blockIdx.x * 64;
  const int t   = threadIdx.x;
  const int w   = __builtin_amdgcn_readfirstlane(t >> 6);
  const int l15 = t & 15;
  const int lhi = (t & 63) >> 4;

  const char* W1B = (const char*)W1b;
  int aoffs[4], aldsb[4];
#pragma unroll
  for (int j = 0; j < 4; ++j) {
    int L16  = j * 256 + t;
    int row  = L16 >> 3;
    int colb = (L16 & 7) * 16;
    aoffs[j] = row * (C1_ * 2) + (colb ^ ((row & 7) << 4));
    aldsb[j] = L16 * 16;
  }
  const int c_l = t & 63;
  const int px0 = (t >> 6) * 16;

#define STAGEA(BUF, KC)                                                        \
  _Pragma("unroll") for (int j = 0; j < 4; ++j)                                \
      gload16(W1B + aoffs[j] + (KC) * 128, (char*)&Ash[BUF][0] + aldsb[j]);
#define LOADB(KC)                                                              \
  _Pragma("unroll") for (int u = 0; u < 4; ++u)                                \
      xv[u] = *reinterpret_cast<const float4*>(                                \
          x + ((size_t)(b * C1_ + (KC) * 64 + c_l)) * HW_ + hw0 + px0 + u * 4);
#define WRITEB(BUF)                                                            \
  _Pragma("unroll") for (int u = 0; u < 4; ++u)                                \
    _Pragma("unroll") for (int e = 0; e < 4; ++e) {                            \
      int px = px0 + u * 4 + e;                                                \
      float vv = (e == 0) ? xv[u].x : (e == 1) ? xv[u].y                       \
               : (e == 2) ? xv[u].z : xv[u].w;                                 \
      Bsh[BUF][px * 64 + (c_l ^ (((u * 4 + e) & 7) << 3))] = f2bf(vv);         \
    }

  f32x4 acc[2][4];
#pragma unroll
  for (int i = 0; i < 2; ++i)
#pragma unroll
    for (int nf = 0; nf < 4; ++nf) acc[i][nf] = (f32x4)0.f;

  const int swzs = (l15 & 7) << 3;
  const int lhi8 = lhi * 8;

  float4 xv[4];
  STAGEA(0, 0);
  LOADB(0);
  WRITEB(0);
  __syncthreads();

  int cur = 0;
  for (int kc = 0; kc < 4; ++kc) {
    if (kc < 3) {
      STAGEA(cur ^ 1, kc + 1);
      LOADB(kc + 1);
    }
    const unsigned short* Ab = &Ash[cur][0];
    const unsigned short* Bb = &Bsh[cur][0];
#pragma unroll
    for (int ks = 0; ks < 2; ++ks) {
      bf16x8 av[2], bv[4];
#pragma unroll
      for (int mf = 0; mf < 2; ++mf) {
        int row = w * 32 + mf * 16 + l15;
        av[mf] = *reinterpret_cast<const bf16x8*>(
            Ab + row * 64 + (((ks << 5) + lhi8) ^ swzs));
      }
#pragma unroll
      for (int nf = 0; nf < 4; ++nf) {
        int row = nf * 16 + l15;
        bv[nf] = *reinterpret_cast<const bf16x8*>(
            Bb + row * 64 + (((ks << 5) + lhi8) ^ swzs));
      }
#pragma unroll
      for (int mf = 0; mf < 2; ++mf)
#pragma unroll
        for (int nf = 0; nf < 4; ++nf)
          acc[mf][nf] = __builtin_amdgcn_mfma_f32_16x16x32_bf16(
              av[mf], bv[nf], acc[mf][nf], 0, 0, 0);
    }
    if (kc < 3) WRITEB(cur ^ 1);
    __syncthreads();
    cur ^= 1;
  }
#undef STAGEA
#undef LOADB
#undef WRITEB

#pragma unroll
  for (int mf = 0; mf < 2; ++mf) {
#pragma unroll
    for (int r = 0; r < 4; ++r) {
      int o = w * 32 + mf * 16 + lhi * 4 + r;
      float s  = g1[o] * rsqrtf(v1[o] + EPS_);
      float sh = b1[o] - m1[o] * s;
#pragma unroll
      for (int nf = 0; nf < 4; ++nf) {
        float val = fmaf(acc[mf][nf][r], s, sh);
        float sig = 1.f / (1.f + __expf(-val));
        h[((size_t)b * Cm_ + o) * HW_ + hw0 + nf * 16 + l15] = f2bf(val * sig);
      }
    }
  }
}

// ---------------- Kernel 2a (round-17: exp2 log2-domain softmax) ------------
__global__ __launch_bounds__(256) void k2a_weights(
    const unsigned short* __restrict__ h,
    const float* __restrict__ Wgt, const float* __restrict__ bgt,
    unsigned short* __restrict__ vt) {
  __shared__ unsigned short ht[Cm_ * 30];     // [c][r(3)][xx(10)] bf16
  __shared__ unsigned short vbuf[8][CN_];     // [px][k = n*128+c] bf16

  const int b  = blockIdx.z;
  const int y  = blockIdx.y;
  const int x0 = blockIdx.x * 8;
  const int t  = threadIdx.x;

  for (int idx = t; idx < Cm_ * 30; idx += 256) {
    int c   = idx / 30;
    int rem = idx - c * 30;
    int r   = rem / 10;
    int xx  = rem - r * 10;
    int gy  = y + r - 1;
    int gx  = x0 + xx - 1;
    unsigned short val = 0;
    if ((unsigned)gy < (unsigned)H_ && (unsigned)gx < (unsigned)W_)
      val = h[((size_t)b * Cm_ + c) * HW_ + gy * W_ + gx];
    ht[idx] = val;
  }
  __syncthreads();

  const int c  = t & 127;
  const int p0 = t >> 7;          // 0 or 1 (wave-uniform)

  float p[4][9];
  {
    float f[3][10];
#pragma unroll
    for (int r = 0; r < 3; ++r) {
      const unsigned int* src =
          reinterpret_cast<const unsigned int*>(&ht[c * 30 + r * 10]);
#pragma unroll
      for (int u = 0; u < 5; ++u) {
        unsigned int d = src[u];
        f[r][2 * u]     = bf2f((unsigned short)(d & 0xffffu));
        f[r][2 * u + 1] = bf2f((unsigned short)(d >> 16));
      }
    }
#pragma unroll
    for (int j = 0; j < 4; ++j)
#pragma unroll
      for (int r = 0; r < 3; ++r)
#pragma unroll
        for (int cc = 0; cc < 3; ++cc)
          p[j][r * 3 + cc] = p0 ? f[r][2 * j + 1 + cc] : f[r][2 * j + cc];
  }

  float wv[9][4];
#pragma unroll
  for (int n = 0; n < 9; ++n) {
    float bgv = bgt[n * 128 + c];
    float wg[9];
#pragma unroll
    for (int i = 0; i < 9; ++i) wg[i] = Wgt[(n * 9 + i) * 128 + c];
#pragma unroll
    for (int j = 0; j < 4; ++j) {
      float a = bgv;
#pragma unroll
      for (int i = 0; i < 9; ++i) a = fmaf(wg[i], p[j][i], a);
      wv[n][j] = a;
    }
  }

#pragma unroll
  for (int j = 0; j < 4; ++j) {
    int px = p0 + 2 * j;
    float e[9], sum = 0.f;
#pragma unroll
    for (int n = 0; n < 9; ++n) {
      e[n] = __builtin_amdgcn_exp2f(wv[n][j]);
      sum += e[n];
    }
    float inv = 1.f / sum;
#pragma unroll
    for (int n = 0; n < 9; ++n)
      vbuf[px][n * 128 + c] = f2bf(p[j][n] * e[n] * inv);
  }
  __syncthreads();

  for (int idx = t; idx < 8 * (CN_ / 8); idx += 256) {   // 1152 chunks
    int px  = idx / 144;
    int off = idx - px * 144;
    const uint4* src = reinterpret_cast<const uint4*>(&vbuf[px][off * 8]);
    int hw = y * W_ + x0 + px;
    uint4* dst = reinterpret_cast<uint4*>(vt + ((size_t)b * HW_ + hw) * CN_ + off * 8);
    *dst = *src;
  }
}

// ---------------- Kernel 2b v4: BK=32, 40 KB LDS, 4 blocks/CU ---------------
// BM=256, BN=64, BK=32, 36 K-iters. 512 thr = 8 waves (4M x 2N).
// Swizzle: chunk ^= (row>>1)&3 (2-way banks = free). Single dispatch round.
__global__ __launch_bounds__(512, 8) void k2b_gemm(
    const unsigned short* __restrict__ Wcb, const unsigned short* __restrict__ vt,
    const float* __restrict__ A2, const float* __restrict__ B2,
    const float* __restrict__ x, float* __restrict__ out) {
  __shared__ alignas(16) unsigned short Ash[2][256 * 32];  // 16 KB each
  __shared__ alignas(16) unsigned short Bsh[2][64 * 32];   //  4 KB each

  const int b   = blockIdx.y;
  const int n0  = blockIdx.x * 64;
  const int t   = threadIdx.x;
  const int w   = __builtin_amdgcn_readfirstlane(t >> 6);
  const int l   = t & 63;
  const int l15 = l & 15;
  const int lhi = l >> 4;
  const int mw  = w >> 1;        // 0..3
  const int nw  = w & 1;         // 0..1

  const char* WcbB = (const char*)Wcb;
  const char* vtB  = (const char*)vt;

  // A staging: 1024 chunks, 2/thread. row = L16>>2, chunk = L16&3.
  int aoffs[2], aldsb[2];
#pragma unroll
  for (int j = 0; j < 2; ++j) {
    int L16  = j * 512 + t;
    int row  = L16 >> 2;
    int ch   = L16 & 3;
    aoffs[j] = row * (CN_ * 2) + ((ch ^ ((row >> 1) & 3)) * 16);
    aldsb[j] = L16 * 16;
  }
  // B staging: 256 chunks, threads 0..255.
  const int brow  = t >> 2;              // 0..63 (t<256)
  const long boff = (long)((size_t)(b * HW_ + n0 + brow) * CN_) * 2 +
                    (((t & 3) ^ ((brow >> 1) & 3)) * 16);
  const int bldsb = t * 16;

#define STAGE(BUF, TT) do {                                                    \
    _Pragma("unroll") for (int j = 0; j < 2; ++j)                              \
      gload16(WcbB + aoffs[j] + (TT) * 64, (char*)&Ash[BUF][0] + aldsb[j]);    \
    if (t < 256)                                                               \
      gload16(vtB + boff + (TT) * 64, (char*)&Bsh[BUF][0] + bldsb);            \
  } while (0)

  f32x4 acc[4][2];
#pragma unroll
  for (int i = 0; i < 4; ++i)
#pragma unroll
    for (int nf = 0; nf < 2; ++nf) acc[i][nf] = (f32x4)0.f;

  STAGE(0, 0);
  __syncthreads();

  int cur = 0;
  for (int tt = 0; tt < 36; ++tt) {
    if (tt < 35) STAGE(cur ^ 1, tt + 1);
    const unsigned short* Ab = &Ash[cur][0];
    const unsigned short* Bb = &Bsh[cur][0];
    bf16x8 av[4], bv[2];
#pragma unroll
    for (int mf = 0; mf < 4; ++mf) {
      int row = mw * 64 + mf * 16 + l15;
      av[mf] = *reinterpret_cast<const bf16x8*>(
          Ab + row * 32 + ((lhi ^ ((row >> 1) & 3)) * 8));
    }
#pragma unroll
    for (int nf = 0; nf < 2; ++nf) {
      int row = nw * 32 + nf * 16 + l15;
      bv[nf] = *reinterpret_cast<const bf16x8*>(
          Bb + row * 32 + ((lhi ^ ((row >> 1) & 3)) * 8));
    }
#pragma unroll
    for (int mf = 0; mf < 4; ++mf)
#pragma unroll
      for (int nf = 0; nf < 2; ++nf)
        acc[mf][nf] = __builtin_amdgcn_mfma_f32_16x16x32_bf16(
            av[mf], bv[nf], acc[mf][nf], 0, 0, 0);
    __syncthreads();
    cur ^= 1;
  }
#undef STAGE

  // epilogue: BN2 + ReLU + residual
#pragma unroll
  for (int mf = 0; mf < 4; ++mf) {
#pragma unroll
    for (int r = 0; r < 4; ++r) {
      int o = mw * 64 + mf * 16 + lhi * 4 + r;
      float sA = A2[o], sB = B2[o];
#pragma unroll
      for (int nf = 0; nf < 2; ++nf) {
        float val = fmaf(acc[mf][nf][r], sA, sB);
        val = fmaxf(val, 0.f);
        size_t idx = ((size_t)b * C2_ + o) * HW_ + n0 + nw * 32 + nf * 16 + l15;
        out[idx] = x[idx] + val;
      }
    }
  }
}

extern "C" void kernel_launch(void* const* d_in, const int* in_sizes, int n_in,
                              void* d_out, int out_size, void* d_ws, size_t ws_size,
                              hipStream_t stream) {
  (void)in_sizes; (void)n_in; (void)out_size; (void)ws_size;
  const float* x   = (const float*)d_in[0];
  const float* W1  = (const float*)d_in[1];
  const float* g1  = (const float*)d_in[2];
  const float* b1  = (const float*)d_in[3];
  const float* m1  = (const float*)d_in[4];
  const float* v1  = (const float*)d_in[5];
  const float* Wg  = (const float*)d_in[6];
  const float* bg  = (const float*)d_in[7];
  const float* gg  = (const float*)d_in[8];
  const float* bgw = (const float*)d_in[9];
  const float* mg  = (const float*)d_in[10];
  const float* vg  = (const float*)d_in[11];
  const float* Wc  = (const float*)d_in[12];
  const float* bc  = (const float*)d_in[13];
  const float* g2  = (const float*)d_in[14];
  const float* b2  = (const float*)d_in[15];
  const float* m2  = (const float*)d_in[16];
  const float* v2  = (const float*)d_in[17];
  float* outp = (float*)d_out;

  // workspace layout (bytes):
  //   h   : bf16 [8][128][6400]      13,107,200   @ 0
  //   vt  : bf16 [8][6400][1152]    117,964,800   @ 13,107,200
  //   Wcb : bf16 [256][1152]            589,824   @ 131,072,000 (K-permuted)
  //   Wgt : f32  [81][128]               41,472   @ 131,661,824 (transposed, *log2e)
  //   bgt : f32  [9][128]                 4,608   @ 131,703,296 (transposed, *log2e)
  //   A2,B2: f32 [256] each               2,048   @ 131,707,904
  //   W1b : bf16 [128][256]              65,536   @ 131,709,952
  char* ws = (char*)d_ws;
  unsigned short* h   = (unsigned short*)ws;
  unsigned short* vt  = (unsigned short*)(ws + 13107200);
  unsigned short* Wcb = (unsigned short*)(ws + 131072000);
  float*          Wgt = (float*)(ws + 131661824);
  float*          bgt = (float*)(ws + 131703296);
  float*          A2  = (float*)(ws + 131707904);
  float*          B2  = A2 + C2_;
  unsigned short* W1b = (unsigned short*)(ws + 131709952);

  k0_prep<<<dim3((C2_ * CN_ + 255) / 256), 256, 0, stream>>>(
      Wc, bc, g2, b2, m2, v2, Wg, bg, gg, bgw, mg, vg, W1,
      Wcb, A2, B2, Wgt, bgt, W1b);

  dim3 grid1(HW_ / 64, B_);
  k1_cv1<<<grid1, 256, 0, stream>>>(x, W1b, g1, b1, m1, v1, h);

  dim3 grid2a(W_ / 8, H_, B_);
  k2a_weights<<<grid2a, 256, 0, stream>>>(h, Wgt, bgt, vt);

  dim3 grid2b(HW_ / 64, B_);
  k2b_gemm<<<grid2b, 512, 0, stream>>>(Wcb, vt, A2, B2, x, outp);
}

// Round 20
// 150.693 us; speedup vs baseline: 1.0511x; 1.0511x over previous
//
#include <hip/hip_runtime.h>
#include <hip/hip_bf16.h>

#define B_   8
#define C1_  256
#define C2_  256
#define Cm_  128    // C_ = C2/2
#define H_   80
#define W_   80
#define HW_  6400
#define CN_  1152   // C_ * 9
#define EPS_ 1e-5f
#define LOG2E_ 1.4426950408889634f

typedef __attribute__((ext_vector_type(8))) short bf16x8;
typedef __attribute__((ext_vector_type(4))) float f32x4;

__device__ inline unsigned short f2bf(float f) {
  union { float f; unsigned int u; } v; v.f = f;
  unsigned int u = v.u;
  unsigned int r = (u + 0x7FFFu + ((u >> 16) & 1u)) >> 16;
  return (unsigned short)r;
}
__device__ inline float bf2f(unsigned short s) {
  union { unsigned int u; float f; } v; v.u = ((unsigned int)s) << 16;
  return v.f;
}
__device__ inline unsigned short bfb(float f) {   // single-cast RNE (compiler path)
  __hip_bfloat16 b = __float2bfloat16(f);
  union { __hip_bfloat16 b; unsigned short u; } v; v.b = b;
  return v.u;
}

__device__ __forceinline__ void gload16(const void* g, void* l) {
  __builtin_amdgcn_global_load_lds(
      (const __attribute__((address_space(1))) void*)g,
      (__attribute__((address_space(3))) void*)l, 16, 0, 0);
}

// ---- Kernel 0: prep (round-17; Wgt/bgt folded with LOG2E) ------------------
__global__ __launch_bounds__(256) void k0_prep(
    const float* __restrict__ Wc, const float* __restrict__ bc,
    const float* __restrict__ g2, const float* __restrict__ b2,
    const float* __restrict__ m2, const float* __restrict__ v2,
    const float* __restrict__ Wg, const float* __restrict__ bg,
    const float* __restrict__ gg, const float* __restrict__ bgw,
    const float* __restrict__ mg, const float* __restrict__ vg,
    const float* __restrict__ W1,
    unsigned short* __restrict__ Wcb, float* __restrict__ A2,
    float* __restrict__ B2, float* __restrict__ Wgt,
    float* __restrict__ bgt, unsigned short* __restrict__ W1b) {
  int idx = blockIdx.x * 256 + threadIdx.x;
  if (idx < C2_ * CN_) {
    int o = idx / CN_;
    int r = idx - o * CN_;
    int n = r >> 7;          // 0..8
    int c = r & 127;         // 0..127
    Wcb[idx] = f2bf(Wc[o * CN_ + c * 9 + n]);
  }
  if (idx < Cm_ * 81) {
    int c  = idx / 81;
    int oi = idx - c * 81;
    int n  = oi / 9;
    float sg = gg[c * 9 + n] * rsqrtf(vg[c * 9 + n] + EPS_);
    Wgt[oi * 128 + c] = Wg[idx] * sg * LOG2E_;
  }
  if (idx < Cm_ * 9) {
    int c = idx / 9;
    int n = idx - c * 9;
    float sg = gg[idx] * rsqrtf(vg[idx] + EPS_);
    bgt[n * 128 + c] = ((bg[idx] - mg[idx]) * sg + bgw[idx]) * LOG2E_;
  }
  if (idx < Cm_ * C1_) W1b[idx] = f2bf(W1[idx]);
  if (idx < C2_) {
    float s = g2[idx] * rsqrtf(v2[idx] + EPS_);
    A2[idx] = s;
    B2[idx] = (bc[idx] - m2[idx]) * s + b2[idx];
  }
}

// ---------------- Kernel 1: h = SiLU(BN1(W1b @ x)) via MFMA (round-12) ------
__global__ __launch_bounds__(256) void k1_cv1(
    const float* __restrict__ x, const unsigned short* __restrict__ W1b,
    const float* __restrict__ g1, const float* __restrict__ b1,
    const float* __restrict__ m1, const float* __restrict__ v1,
    unsigned short* __restrict__ h) {
  __shared__ alignas(16) unsigned short Ash[2][128 * 64];
  __shared__ alignas(16) unsigned short Bsh[2][64 * 64];

  const int b   = blockIdx.y;
  const int hw0 = blockIdx.x * 64;
  const int t   = threadIdx.x;
  const int w   = __builtin_amdgcn_readfirstlane(t >> 6);
  const int l15 = t & 15;
  const int lhi = (t & 63) >> 4;

  const char* W1B = (const char*)W1b;
  int aoffs[4], aldsb[4];
#pragma unroll
  for (int j = 0; j < 4; ++j) {
    int L16  = j * 256 + t;
    int row  = L16 >> 3;
    int colb = (L16 & 7) * 16;
    aoffs[j] = row * (C1_ * 2) + (colb ^ ((row & 7) << 4));
    aldsb[j] = L16 * 16;
  }
  const int c_l = t & 63;
  const int px0 = (t >> 6) * 16;

#define STAGEA(BUF, KC)                                                        \
  _Pragma("unroll") for (int j = 0; j < 4; ++j)                                \
      gload16(W1B + aoffs[j] + (KC) * 128, (char*)&Ash[BUF][0] + aldsb[j]);
#define LOADB(KC)                                                              \
  _Pragma("unroll") for (int u = 0; u < 4; ++u)                                \
      xv[u] = *reinterpret_cast<const float4*>(                                \
          x + ((size_t)(b * C1_ + (KC) * 64 + c_l)) * HW_ + hw0 + px0 + u * 4);
#define WRITEB(BUF)                                                            \
  _Pragma("unroll") for (int u = 0; u < 4; ++u)                                \
    _Pragma("unroll") for (int e = 0; e < 4; ++e) {                            \
      int px = px0 + u * 4 + e;                                                \
      float vv = (e == 0) ? xv[u].x : (e == 1) ? xv[u].y                       \
               : (e == 2) ? xv[u].z : xv[u].w;                                 \
      Bsh[BUF][px * 64 + (c_l ^ (((u * 4 + e) & 7) << 3))] = f2bf(vv);         \
    }

  f32x4 acc[2][4];
#pragma unroll
  for (int i = 0; i < 2; ++i)
#pragma unroll
    for (int nf = 0; nf < 4; ++nf) acc[i][nf] = (f32x4)0.f;

  const int swzs = (l15 & 7) << 3;
  const int lhi8 = lhi * 8;

  float4 xv[4];
  STAGEA(0, 0);
  LOADB(0);
  WRITEB(0);
  __syncthreads();

  int cur = 0;
  for (int kc = 0; kc < 4; ++kc) {
    if (kc < 3) {
      STAGEA(cur ^ 1, kc + 1);
      LOADB(kc + 1);
    }
    const unsigned short* Ab = &Ash[cur][0];
    const unsigned short* Bb = &Bsh[cur][0];
#pragma unroll
    for (int ks = 0; ks < 2; ++ks) {
      bf16x8 av[2], bv[4];
#pragma unroll
      for (int mf = 0; mf < 2; ++mf) {
        int row = w * 32 + mf * 16 + l15;
        av[mf] = *reinterpret_cast<const bf16x8*>(
            Ab + row * 64 + (((ks << 5) + lhi8) ^ swzs));
      }
#pragma unroll
      for (int nf = 0; nf < 4; ++nf) {
        int row = nf * 16 + l15;
        bv[nf] = *reinterpret_cast<const bf16x8*>(
            Bb + row * 64 + (((ks << 5) + lhi8) ^ swzs));
      }
#pragma unroll
      for (int mf = 0; mf < 2; ++mf)
#pragma unroll
        for (int nf = 0; nf < 4; ++nf)
          acc[mf][nf] = __builtin_amdgcn_mfma_f32_16x16x32_bf16(
              av[mf], bv[nf], acc[mf][nf], 0, 0, 0);
    }
    if (kc < 3) WRITEB(cur ^ 1);
    __syncthreads();
    cur ^= 1;
  }
#undef STAGEA
#undef LOADB
#undef WRITEB

#pragma unroll
  for (int mf = 0; mf < 2; ++mf) {
#pragma unroll
    for (int r = 0; r < 4; ++r) {
      int o = w * 32 + mf * 16 + lhi * 4 + r;
      float s  = g1[o] * rsqrtf(v1[o] + EPS_);
      float sh = b1[o] - m1[o] * s;
#pragma unroll
      for (int nf = 0; nf < 4; ++nf) {
        float val = fmaf(acc[mf][nf][r], s, sh);
        float sig = 1.f / (1.f + __expf(-val));
        h[((size_t)b * Cm_ + o) * HW_ + hw0 + nf * 16 + l15] = f2bf(val * sig);
      }
    }
  }
}

// ---------------- Kernel 2a (round-17 + single-cast bf16 stores) ------------
__global__ __launch_bounds__(256) void k2a_weights(
    const unsigned short* __restrict__ h,
    const float* __restrict__ Wgt, const float* __restrict__ bgt,
    unsigned short* __restrict__ vt) {
  __shared__ unsigned short ht[Cm_ * 30];     // [c][r(3)][xx(10)] bf16
  __shared__ unsigned short vbuf[8][CN_];     // [px][k = n*128+c] bf16

  const int b  = blockIdx.z;
  const int y  = blockIdx.y;
  const int x0 = blockIdx.x * 8;
  const int t  = threadIdx.x;

  for (int idx = t; idx < Cm_ * 30; idx += 256) {
    int c   = idx / 30;
    int rem = idx - c * 30;
    int r   = rem / 10;
    int xx  = rem - r * 10;
    int gy  = y + r - 1;
    int gx  = x0 + xx - 1;
    unsigned short val = 0;
    if ((unsigned)gy < (unsigned)H_ && (unsigned)gx < (unsigned)W_)
      val = h[((size_t)b * Cm_ + c) * HW_ + gy * W_ + gx];
    ht[idx] = val;
  }
  __syncthreads();

  const int c  = t & 127;
  const int p0 = t >> 7;          // 0 or 1 (wave-uniform)

  float p[4][9];
  {
    float f[3][10];
#pragma unroll
    for (int r = 0; r < 3; ++r) {
      const unsigned int* src =
          reinterpret_cast<const unsigned int*>(&ht[c * 30 + r * 10]);
#pragma unroll
      for (int u = 0; u < 5; ++u) {
        unsigned int d = src[u];
        f[r][2 * u]     = bf2f((unsigned short)(d & 0xffffu));
        f[r][2 * u + 1] = bf2f((unsigned short)(d >> 16));
      }
    }
#pragma unroll
    for (int j = 0; j < 4; ++j)
#pragma unroll
      for (int r = 0; r < 3; ++r)
#pragma unroll
        for (int cc = 0; cc < 3; ++cc)
          p[j][r * 3 + cc] = p0 ? f[r][2 * j + 1 + cc] : f[r][2 * j + cc];
  }

  float wv[9][4];
#pragma unroll
  for (int n = 0; n < 9; ++n) {
    float bgv = bgt[n * 128 + c];
    float wg[9];
#pragma unroll
    for (int i = 0; i < 9; ++i) wg[i] = Wgt[(n * 9 + i) * 128 + c];
#pragma unroll
    for (int j = 0; j < 4; ++j) {
      float a = bgv;
#pragma unroll
      for (int i = 0; i < 9; ++i) a = fmaf(wg[i], p[j][i], a);
      wv[n][j] = a;
    }
  }

#pragma unroll
  for (int j = 0; j < 4; ++j) {
    int px = p0 + 2 * j;
    float e[9], sum = 0.f;
#pragma unroll
    for (int n = 0; n < 9; ++n) {
      e[n] = __builtin_amdgcn_exp2f(wv[n][j]);
      sum += e[n];
    }
    float inv = 1.f / sum;
#pragma unroll
    for (int n = 0; n < 9; ++n)
      vbuf[px][n * 128 + c] = bfb(p[j][n] * e[n] * inv);
  }
  __syncthreads();

  for (int idx = t; idx < 8 * (CN_ / 8); idx += 256) {   // 1152 chunks
    int px  = idx / 144;
    int off = idx - px * 144;
    const uint4* src = reinterpret_cast<const uint4*>(&vbuf[px][off * 8]);
    int hw = y * W_ + x0 + px;
    uint4* dst = reinterpret_cast<uint4*>(vt + ((size_t)b * HW_ + hw) * CN_ + off * 8);
    *dst = *src;
  }
}

// ---------------- Kernel 2b v3 (proven BK=64): 2-phase pipelined MFMA GEMM --
__global__ __launch_bounds__(512, 4) void k2b_gemm(
    const unsigned short* __restrict__ Wcb, const unsigned short* __restrict__ vt,
    const float* __restrict__ A2, const float* __restrict__ B2,
    const float* __restrict__ x, float* __restrict__ out) {
  __shared__ alignas(16) unsigned short Ash[2][256 * 64];
  __shared__ alignas(16) unsigned short Bsh[2][64 * 64];

  const int b   = blockIdx.y;
  const int n0  = blockIdx.x * 64;
  const int t   = threadIdx.x;
  const int w   = __builtin_amdgcn_readfirstlane(t >> 6);
  const int l   = t & 63;
  const int l15 = l & 15;
  const int lhi = l >> 4;
  const int mw  = w >> 1;
  const int nw  = w & 1;

  const char* WcbB = (const char*)Wcb;
  const char* vtB  = (const char*)vt;
  int  aoffs[4], aldsb[4];
#pragma unroll
  for (int j = 0; j < 4; ++j) {
    int L16  = (w * 4 + j) * 64 + l;
    int row  = L16 >> 3;
    int colb = (L16 & 7) * 16;
    aoffs[j] = row * (CN_ * 2) + (colb ^ ((row & 7) << 4));
    aldsb[j] = L16 * 16;
  }
  const int bpx  = t >> 3;
  const long boff = (long)((size_t)(b * HW_ + n0 + bpx) * CN_) * 2 +
                    (((t & 7) * 16) ^ ((bpx & 7) << 4));
  const int bldsb = t * 16;

#define STAGE(BUF, TT) do {                                                    \
    _Pragma("unroll") for (int j = 0; j < 4; ++j)                              \
      gload16(WcbB + aoffs[j] + (TT) * 128, (char*)&Ash[BUF][0] + aldsb[j]);   \
    gload16(vtB + boff + (TT) * 128, (char*)&Bsh[BUF][0] + bldsb);             \
  } while (0)

  f32x4 acc[4][2];
#pragma unroll
  for (int i = 0; i < 4; ++i)
#pragma unroll
    for (int nf = 0; nf < 2; ++nf) acc[i][nf] = (f32x4)0.f;

  const int swzs = (l15 & 7) << 3;
  const int lhi8 = lhi * 8;

  STAGE(0, 0);
  __syncthreads();

  int cur = 0;
  for (int tt = 0; tt < 18; ++tt) {
    if (tt < 17) STAGE(cur ^ 1, tt + 1);
    const unsigned short* Ab = &Ash[cur][0];
    const unsigned short* Bb = &Bsh[cur][0];
#pragma unroll
    for (int ks = 0; ks < 2; ++ks) {
      bf16x8 av[4], bv[2];
#pragma unroll
      for (int mf = 0; mf < 4; ++mf) {
        int row = mw * 64 + mf * 16 + l15;
        av[mf] = *reinterpret_cast<const bf16x8*>(
            Ab + row * 64 + (((ks << 5) + lhi8) ^ swzs));
      }
#pragma unroll
      for (int nf = 0; nf < 2; ++nf) {
        int row = nw * 32 + nf * 16 + l15;
        bv[nf] = *reinterpret_cast<const bf16x8*>(
            Bb + row * 64 + (((ks << 5) + lhi8) ^ swzs));
      }
#pragma unroll
      for (int mf = 0; mf < 4; ++mf)
#pragma unroll
        for (int nf = 0; nf < 2; ++nf)
          acc[mf][nf] = __builtin_amdgcn_mfma_f32_16x16x32_bf16(
              av[mf], bv[nf], acc[mf][nf], 0, 0, 0);
    }
    __syncthreads();
    cur ^= 1;
  }
#undef STAGE

#pragma unroll
  for (int mf = 0; mf < 4; ++mf) {
#pragma unroll
    for (int r = 0; r < 4; ++r) {
      int o = mw * 64 + mf * 16 + lhi * 4 + r;
      float sA = A2[o], sB = B2[o];
#pragma unroll
      for (int nf = 0; nf < 2; ++nf) {
        float val = fmaf(acc[mf][nf][r], sA, sB);
        val = fmaxf(val, 0.f);
        size_t idx = ((size_t)b * C2_ + o) * HW_ + n0 + nw * 32 + nf * 16 + l15;
        out[idx] = x[idx] + val;
      }
    }
  }
}

extern "C" void kernel_launch(void* const* d_in, const int* in_sizes, int n_in,
                              void* d_out, int out_size, void* d_ws, size_t ws_size,
                              hipStream_t stream) {
  (void)in_sizes; (void)n_in; (void)out_size; (void)ws_size;
  const float* x   = (const float*)d_in[0];
  const float* W1  = (const float*)d_in[1];
  const float* g1  = (const float*)d_in[2];
  const float* b1  = (const float*)d_in[3];
  const float* m1  = (const float*)d_in[4];
  const float* v1  = (const float*)d_in[5];
  const float* Wg  = (const float*)d_in[6];
  const float* bg  = (const float*)d_in[7];
  const float* gg  = (const float*)d_in[8];
  const float* bgw = (const float*)d_in[9];
  const float* mg  = (const float*)d_in[10];
  const float* vg  = (const float*)d_in[11];
  const float* Wc  = (const float*)d_in[12];
  const float* bc  = (const float*)d_in[13];
  const float* g2  = (const float*)d_in[14];
  const float* b2  = (const float*)d_in[15];
  const float* m2  = (const float*)d_in[16];
  const float* v2  = (const float*)d_in[17];
  float* outp = (float*)d_out;

  // workspace layout (bytes):
  //   h   : bf16 [8][128][6400]      13,107,200   @ 0
  //   vt  : bf16 [8][6400][1152]    117,964,800   @ 13,107,200
  //   Wcb : bf16 [256][1152]            589,824   @ 131,072,000 (K-permuted)
  //   Wgt : f32  [81][128]               41,472   @ 131,661,824 (transposed, *log2e)
  //   bgt : f32  [9][128]                 4,608   @ 131,703,296 (transposed, *log2e)
  //   A2,B2: f32 [256] each               2,048   @ 131,707,904
  //   W1b : bf16 [128][256]              65,536   @ 131,709,952
  char* ws = (char*)d_ws;
  unsigned short* h   = (unsigned short*)ws;
  unsigned short* vt  = (unsigned short*)(ws + 13107200);
  unsigned short* Wcb = (unsigned short*)(ws + 131072000);
  float*          Wgt = (float*)(ws + 131661824);
  float*          bgt = (float*)(ws + 131703296);
  float*          A2  = (float*)(ws + 131707904);
  float*          B2  = A2 + C2_;
  unsigned short* W1b = (unsigned short*)(ws + 131709952);

  k0_prep<<<dim3((C2_ * CN_ + 255) / 256), 256, 0, stream>>>(
      Wc, bc, g2, b2, m2, v2, Wg, bg, gg, bgw, mg, vg, W1,
      Wcb, A2, B2, Wgt, bgt, W1b);

  dim3 grid1(HW_ / 64, B_);
  k1_cv1<<<grid1, 256, 0, stream>>>(x, W1b, g1, b1, m1, v1, h);

  dim3 grid2a(W_ / 8, H_, B_);
  k2a_weights<<<grid2a, 256, 0, stream>>>(h, Wgt, bgt, vt);

  dim3 grid2b(HW_ / 64, B_);
  k2b_gemm<<<grid2b, 512, 0, stream>>>(Wcb, vt, A2, B2, x, outp);
}

// Round 23
// 145.360 us; speedup vs baseline: 1.0896x; 1.0367x over previous
//
#include <hip/hip_runtime.h>
#include <hip/hip_bf16.h>

#define B_   8
#define C1_  256
#define C2_  256
#define Cm_  128    // C_ = C2/2
#define H_   80
#define W_   80
#define HW_  6400
#define CN_  1152   // C_ * 9
#define EPS_ 1e-5f
#define LOG2E_ 1.4426950408889634f

typedef __attribute__((ext_vector_type(8))) short bf16x8;
typedef __attribute__((ext_vector_type(4))) float f32x4;

__device__ inline unsigned short f2bf(float f) {
  union { float f; unsigned int u; } v; v.f = f;
  unsigned int u = v.u;
  unsigned int r = (u + 0x7FFFu + ((u >> 16) & 1u)) >> 16;
  return (unsigned short)r;
}
__device__ inline float bf2f(unsigned short s) {
  union { unsigned int u; float f; } v; v.u = ((unsigned int)s) << 16;
  return v.f;
}
__device__ inline unsigned short bfb(float f) {   // single-cast RNE (compiler path)
  __hip_bfloat16 b = __float2bfloat16(f);
  union { __hip_bfloat16 b; unsigned short u; } v; v.b = b;
  return v.u;
}

__device__ __forceinline__ void gload16(const void* g, void* l) {
  __builtin_amdgcn_global_load_lds(
      (const __attribute__((address_space(1))) void*)g,
      (__attribute__((address_space(3))) void*)l, 16, 0, 0);
}

// ---- Kernel 0: prep (round-17; Wgt/bgt folded with LOG2E) ------------------
__global__ __launch_bounds__(256) void k0_prep(
    const float* __restrict__ Wc, const float* __restrict__ bc,
    const float* __restrict__ g2, const float* __restrict__ b2,
    const float* __restrict__ m2, const float* __restrict__ v2,
    const float* __restrict__ Wg, const float* __restrict__ bg,
    const float* __restrict__ gg, const float* __restrict__ bgw,
    const float* __restrict__ mg, const float* __restrict__ vg,
    const float* __restrict__ W1,
    unsigned short* __restrict__ Wcb, float* __restrict__ A2,
    float* __restrict__ B2, float* __restrict__ Wgt,
    float* __restrict__ bgt, unsigned short* __restrict__ W1b) {
  int idx = blockIdx.x * 256 + threadIdx.x;
  if (idx < C2_ * CN_) {
    int o = idx / CN_;
    int r = idx - o * CN_;
    int n = r >> 7;          // 0..8
    int c = r & 127;         // 0..127
    Wcb[idx] = f2bf(Wc[o * CN_ + c * 9 + n]);
  }
  if (idx < Cm_ * 81) {
    int c  = idx / 81;
    int oi = idx - c * 81;
    int n  = oi / 9;
    float sg = gg[c * 9 + n] * rsqrtf(vg[c * 9 + n] + EPS_);
    Wgt[oi * 128 + c] = Wg[idx] * sg * LOG2E_;
  }
  if (idx < Cm_ * 9) {
    int c = idx / 9;
    int n = idx - c * 9;
    float sg = gg[idx] * rsqrtf(vg[idx] + EPS_);
    bgt[n * 128 + c] = ((bg[idx] - mg[idx]) * sg + bgw[idx]) * LOG2E_;
  }
  if (idx < Cm_ * C1_) W1b[idx] = f2bf(W1[idx]);
  if (idx < C2_) {
    float s = g2[idx] * rsqrtf(v2[idx] + EPS_);
    A2[idx] = s;
    B2[idx] = (bc[idx] - m2[idx]) * s + b2[idx];
  }
}

// ---------------- Kernel 1: h = SiLU(BN1(W1b @ x)) via MFMA (round-12) ------
__global__ __launch_bounds__(256) void k1_cv1(
    const float* __restrict__ x, const unsigned short* __restrict__ W1b,
    const float* __restrict__ g1, const float* __restrict__ b1,
    const float* __restrict__ m1, const float* __restrict__ v1,
    unsigned short* __restrict__ h) {
  __shared__ alignas(16) unsigned short Ash[2][128 * 64];
  __shared__ alignas(16) unsigned short Bsh[2][64 * 64];

  const int b   = blockIdx.y;
  const int hw0 = blockIdx.x * 64;
  const int t   = threadIdx.x;
  const int w   = __builtin_amdgcn_readfirstlane(t >> 6);
  const int l15 = t & 15;
  const int lhi = (t & 63) >> 4;

  const char* W1B = (const char*)W1b;
  int aoffs[4], aldsb[4];
#pragma unroll
  for (int j = 0; j < 4; ++j) {
    int L16  = j * 256 + t;
    int row  = L16 >> 3;
    int colb = (L16 & 7) * 16;
    aoffs[j] = row * (C1_ * 2) + (colb ^ ((row & 7) << 4));
    aldsb[j] = L16 * 16;
  }
  const int c_l = t & 63;
  const int px0 = (t >> 6) * 16;

#define STAGEA(BUF, KC)                                                        \
  _Pragma("unroll") for (int j = 0; j < 4; ++j)                                \
      gload16(W1B + aoffs[j] + (KC) * 128, (char*)&Ash[BUF][0] + aldsb[j]);
#define LOADB(KC)                                                              \
  _Pragma("unroll") for (int u = 0; u < 4; ++u)                                \
      xv[u] = *reinterpret_cast<const float4*>(                                \
          x + ((size_t)(b * C1_ + (KC) * 64 + c_l)) * HW_ + hw0 + px0 + u * 4);
#define WRITEB(BUF)                                                            \
  _Pragma("unroll") for (int u = 0; u < 4; ++u)                                \
    _Pragma("unroll") for (int e = 0; e < 4; ++e) {                            \
      int px = px0 + u * 4 + e;                                                \
      float vv = (e == 0) ? xv[u].x : (e == 1) ? xv[u].y                       \
               : (e == 2) ? xv[u].z : xv[u].w;                                 \
      Bsh[BUF][px * 64 + (c_l ^ (((u * 4 + e) & 7) << 3))] = f2bf(vv);         \
    }

  f32x4 acc[2][4];
#pragma unroll
  for (int i = 0; i < 2; ++i)
#pragma unroll
    for (int nf = 0; nf < 4; ++nf) acc[i][nf] = (f32x4)0.f;

  const int swzs = (l15 & 7) << 3;
  const int lhi8 = lhi * 8;

  float4 xv[4];
  STAGEA(0, 0);
  LOADB(0);
  WRITEB(0);
  __syncthreads();

  int cur = 0;
  for (int kc = 0; kc < 4; ++kc) {
    if (kc < 3) {
      STAGEA(cur ^ 1, kc + 1);
      LOADB(kc + 1);
    }
    const unsigned short* Ab = &Ash[cur][0];
    const unsigned short* Bb = &Bsh[cur][0];
#pragma unroll
    for (int ks = 0; ks < 2; ++ks) {
      bf16x8 av[2], bv[4];
#pragma unroll
      for (int mf = 0; mf < 2; ++mf) {
        int row = w * 32 + mf * 16 + l15;
        av[mf] = *reinterpret_cast<const bf16x8*>(
            Ab + row * 64 + (((ks << 5) + lhi8) ^ swzs));
      }
#pragma unroll
      for (int nf = 0; nf < 4; ++nf) {
        int row = nf * 16 + l15;
        bv[nf] = *reinterpret_cast<const bf16x8*>(
            Bb + row * 64 + (((ks << 5) + lhi8) ^ swzs));
      }
#pragma unroll
      for (int mf = 0; mf < 2; ++mf)
#pragma unroll
        for (int nf = 0; nf < 4; ++nf)
          acc[mf][nf] = __builtin_amdgcn_mfma_f32_16x16x32_bf16(
              av[mf], bv[nf], acc[mf][nf], 0, 0, 0);
    }
    if (kc < 3) WRITEB(cur ^ 1);
    __syncthreads();
    cur ^= 1;
  }
#undef STAGEA
#undef LOADB
#undef WRITEB

#pragma unroll
  for (int mf = 0; mf < 2; ++mf) {
#pragma unroll
    for (int r = 0; r < 4; ++r) {
      int o = w * 32 + mf * 16 + lhi * 4 + r;
      float s  = g1[o] * rsqrtf(v1[o] + EPS_);
      float sh = b1[o] - m1[o] * s;
#pragma unroll
      for (int nf = 0; nf < 4; ++nf) {
        float val = fmaf(acc[mf][nf][r], s, sh);
        float sig = 1.f / (1.f + __expf(-val));
        h[((size_t)b * Cm_ + o) * HW_ + hw0 + nf * 16 + l15] = f2bf(val * sig);
      }
    }
  }
}

// ---------------- Kernel 2a (round-20: exp2 softmax + single-cast stores) ---
__global__ __launch_bounds__(256) void k2a_weights(
    const unsigned short* __restrict__ h,
    const float* __restrict__ Wgt, const float* __restrict__ bgt,
    unsigned short* __restrict__ vt) {
  __shared__ unsigned short ht[Cm_ * 30];     // [c][r(3)][xx(10)] bf16
  __shared__ unsigned short vbuf[8][CN_];     // [px][k = n*128+c] bf16

  const int b  = blockIdx.z;
  const int y  = blockIdx.y;
  const int x0 = blockIdx.x * 8;
  const int t  = threadIdx.x;

  for (int idx = t; idx < Cm_ * 30; idx += 256) {
    int c   = idx / 30;
    int rem = idx - c * 30;
    int r   = rem / 10;
    int xx  = rem - r * 10;
    int gy  = y + r - 1;
    int gx  = x0 + xx - 1;
    unsigned short val = 0;
    if ((unsigned)gy < (unsigned)H_ && (unsigned)gx < (unsigned)W_)
      val = h[((size_t)b * Cm_ + c) * HW_ + gy * W_ + gx];
    ht[idx] = val;
  }
  __syncthreads();

  const int c  = t & 127;
  const int p0 = t >> 7;          // 0 or 1 (wave-uniform)

  float p[4][9];
  {
    float f[3][10];
#pragma unroll
    for (int r = 0; r < 3; ++r) {
      const unsigned int* src =
          reinterpret_cast<const unsigned int*>(&ht[c * 30 + r * 10]);
#pragma unroll
      for (int u = 0; u < 5; ++u) {
        unsigned int d = src[u];
        f[r][2 * u]     = bf2f((unsigned short)(d & 0xffffu));
        f[r][2 * u + 1] = bf2f((unsigned short)(d >> 16));
      }
    }
#pragma unroll
    for (int j = 0; j < 4; ++j)
#pragma unroll
      for (int r = 0; r < 3; ++r)
#pragma unroll
        for (int cc = 0; cc < 3; ++cc)
          p[j][r * 3 + cc] = p0 ? f[r][2 * j + 1 + cc] : f[r][2 * j + cc];
  }

  float wv[9][4];
#pragma unroll
  for (int n = 0; n < 9; ++n) {
    float bgv = bgt[n * 128 + c];
    float wg[9];
#pragma unroll
    for (int i = 0; i < 9; ++i) wg[i] = Wgt[(n * 9 + i) * 128 + c];
#pragma unroll
    for (int j = 0; j < 4; ++j) {
      float a = bgv;
#pragma unroll
      for (int i = 0; i < 9; ++i) a = fmaf(wg[i], p[j][i], a);
      wv[n][j] = a;
    }
  }

#pragma unroll
  for (int j = 0; j < 4; ++j) {
    int px = p0 + 2 * j;
    float e[9], sum = 0.f;
#pragma unroll
    for (int n = 0; n < 9; ++n) {
      e[n] = __builtin_amdgcn_exp2f(wv[n][j]);
      sum += e[n];
    }
    float inv = 1.f / sum;
#pragma unroll
    for (int n = 0; n < 9; ++n)
      vbuf[px][n * 128 + c] = bfb(p[j][n] * e[n] * inv);
  }
  __syncthreads();

  for (int idx = t; idx < 8 * (CN_ / 8); idx += 256) {   // 1152 chunks
    int px  = idx / 144;
    int off = idx - px * 144;
    const uint4* src = reinterpret_cast<const uint4*>(&vbuf[px][off * 8]);
    int hw = y * W_ + x0 + px;
    uint4* dst = reinterpret_cast<uint4*>(vt + ((size_t)b * HW_ + hw) * CN_ + off * 8);
    *dst = *src;
  }
}

// ---------------- Kernel 2b v5: BK=64, 2-deep prefetch, counted vmcnt -------
// BM=256, BN=64, BK=64, 18 K-tiles. 512 thr = 8 waves (4M x 2N).
// Raw s_barrier + s_waitcnt vmcnt(5): tile t+2 loads stay in flight across
// the barrier (T4); never drain to 0 in the main loop.
__global__ __launch_bounds__(512, 4) void k2b_gemm(
    const unsigned short* __restrict__ Wcb, const unsigned short* __restrict__ vt,
    const float* __restrict__ A2, const float* __restrict__ B2,
    const float* __restrict__ x, float* __restrict__ out) {
  __shared__ alignas(16) unsigned short Ash[2][256 * 64];
  __shared__ alignas(16) unsigned short Bsh[2][64 * 64];

  const int b   = blockIdx.y;
  const int n0  = blockIdx.x * 64;
  const int t   = threadIdx.x;
  const int w   = __builtin_amdgcn_readfirstlane(t >> 6);
  const int l   = t & 63;
  const int l15 = l & 15;
  const int lhi = l >> 4;
  const int mw  = w >> 1;
  const int nw  = w & 1;

  const char* WcbB = (const char*)Wcb;
  const char* vtB  = (const char*)vt;
  int  aoffs[4], aldsb[4];
#pragma unroll
  for (int j = 0; j < 4; ++j) {
    int L16  = (w * 4 + j) * 64 + l;
    int row  = L16 >> 3;
    int colb = (L16 & 7) * 16;
    aoffs[j] = row * (CN_ * 2) + (colb ^ ((row & 7) << 4));
    aldsb[j] = L16 * 16;
  }
  const int bpx  = t >> 3;
  const long boff = (long)((size_t)(b * HW_ + n0 + bpx) * CN_) * 2 +
                    (((t & 7) * 16) ^ ((bpx & 7) << 4));
  const int bldsb = t * 16;

#define STAGE(BUF, TT) do {                                                    \
    _Pragma("unroll") for (int j = 0; j < 4; ++j)                              \
      gload16(WcbB + aoffs[j] + (TT) * 128, (char*)&Ash[BUF][0] + aldsb[j]);   \
    gload16(vtB + boff + (TT) * 128, (char*)&Bsh[BUF][0] + bldsb);             \
  } while (0)

  f32x4 acc[4][2];
#pragma unroll
  for (int i = 0; i < 4; ++i)
#pragma unroll
    for (int nf = 0; nf < 2; ++nf) acc[i][nf] = (f32x4)0.f;

  const int swzs = (l15 & 7) << 3;
  const int lhi8 = lhi * 8;

  // prologue: tiles 0 and 1 in flight (10 loads); wait for tile 0 only.
  STAGE(0, 0);
  STAGE(1, 1);
  asm volatile("s_waitcnt vmcnt(5)" ::: "memory");
  __builtin_amdgcn_s_barrier();

  for (int tt = 0; tt < 18; ++tt) {
    const unsigned short* Ab = &Ash[tt & 1][0];
    const unsigned short* Bb = &Bsh[tt & 1][0];
#pragma unroll
    for (int ks = 0; ks < 2; ++ks) {
      bf16x8 av[4], bv[2];
#pragma unroll
      for (int mf = 0; mf < 4; ++mf) {
        int row = mw * 64 + mf * 16 + l15;
        av[mf] = *reinterpret_cast<const bf16x8*>(
            Ab + row * 64 + (((ks << 5) + lhi8) ^ swzs));
      }
#pragma unroll
      for (int nf = 0; nf < 2; ++nf) {
        int row = nw * 32 + nf * 16 + l15;
        bv[nf] = *reinterpret_cast<const bf16x8*>(
            Bb + row * 64 + (((ks << 5) + lhi8) ^ swzs));
      }
#pragma unroll
      for (int mf = 0; mf < 4; ++mf)
#pragma unroll
        for (int nf = 0; nf < 2; ++nf)
          acc[mf][nf] = __builtin_amdgcn_mfma_f32_16x16x32_bf16(
              av[mf], bv[nf], acc[mf][nf], 0, 0, 0);
    }
    __builtin_amdgcn_s_barrier();          // all waves done reading buf[tt&1]
    if (tt + 2 < 18) {
      STAGE(tt & 1, tt + 2);               // in flight: tile t+1 (5) + t+2 (5)
      asm volatile("s_waitcnt vmcnt(5)" ::: "memory");   // tile t+1 landed
    } else {
      asm volatile("s_waitcnt vmcnt(0)" ::: "memory");   // tail drain
    }
    __builtin_amdgcn_s_barrier();          // buf[(tt+1)&1] ready for all waves
  }
#undef STAGE

#pragma unroll
  for (int mf = 0; mf < 4; ++mf) {
#pragma unroll
    for (int r = 0; r < 4; ++r) {
      int o = mw * 64 + mf * 16 + lhi * 4 + r;
      float sA = A2[o], sB = B2[o];
#pragma unroll
      for (int nf = 0; nf < 2; ++nf) {
        float val = fmaf(acc[mf][nf][r], sA, sB);
        val = fmaxf(val, 0.f);
        size_t idx = ((size_t)b * C2_ + o) * HW_ + n0 + nw * 32 + nf * 16 + l15;
        out[idx] = x[idx] + val;
      }
    }
  }
}

extern "C" void kernel_launch(void* const* d_in, const int* in_sizes, int n_in,
                              void* d_out, int out_size, void* d_ws, size_t ws_size,
                              hipStream_t stream) {
  (void)in_sizes; (void)n_in; (void)out_size; (void)ws_size;
  const float* x   = (const float*)d_in[0];
  const float* W1  = (const float*)d_in[1];
  const float* g1  = (const float*)d_in[2];
  const float* b1  = (const float*)d_in[3];
  const float* m1  = (const float*)d_in[4];
  const float* v1  = (const float*)d_in[5];
  const float* Wg  = (const float*)d_in[6];
  const float* bg  = (const float*)d_in[7];
  const float* gg  = (const float*)d_in[8];
  const float* bgw = (const float*)d_in[9];
  const float* mg  = (const float*)d_in[10];
  const float* vg  = (const float*)d_in[11];
  const float* Wc  = (const float*)d_in[12];
  const float* bc  = (const float*)d_in[13];
  const float* g2  = (const float*)d_in[14];
  const float* b2  = (const float*)d_in[15];
  const float* m2  = (const float*)d_in[16];
  const float* v2  = (const float*)d_in[17];
  float* outp = (float*)d_out;

  // workspace layout (bytes):
  //   h   : bf16 [8][128][6400]      13,107,200   @ 0
  //   vt  : bf16 [8][6400][1152]    117,964,800   @ 13,107,200
  //   Wcb : bf16 [256][1152]            589,824   @ 131,072,000 (K-permuted)
  //   Wgt : f32  [81][128]               41,472   @ 131,661,824 (transposed, *log2e)
  //   bgt : f32  [9][128]                 4,608   @ 131,703,296 (transposed, *log2e)
  //   A2,B2: f32 [256] each               2,048   @ 131,707,904
  //   W1b : bf16 [128][256]              65,536   @ 131,709,952
  char* ws = (char*)d_ws;
  unsigned short* h   = (unsigned short*)ws;
  unsigned short* vt  = (unsigned short*)(ws + 13107200);
  unsigned short* Wcb = (unsigned short*)(ws + 131072000);
  float*          Wgt = (float*)(ws + 131661824);
  float*          bgt = (float*)(ws + 131703296);
  float*          A2  = (float*)(ws + 131707904);
  float*          B2  = A2 + C2_;
  unsigned short* W1b = (unsigned short*)(ws + 131709952);

  k0_prep<<<dim3((C2_ * CN_ + 255) / 256), 256, 0, stream>>>(
      Wc, bc, g2, b2, m2, v2, Wg, bg, gg, bgw, mg, vg, W1,
      Wcb, A2, B2, Wgt, bgt, W1b);

  dim3 grid1(HW_ / 64, B_);
  k1_cv1<<<grid1, 256, 0, stream>>>(x, W1b, g1, b1, m1, v1, h);

  dim3 grid2a(W_ / 8, H_, B_);
  k2a_weights<<<grid2a, 256, 0, stream>>>(h, Wgt, bgt, vt);

  dim3 grid2b(HW_ / 64, B_);
  k2b_gemm<<<grid2b, 512, 0, stream>>>(Wcb, vt, A2, B2, x, outp);
}